// Round 2
// 751.704 us; speedup vs baseline: 1.0468x; 1.0468x over previous
//
#include <hip/hip_runtime.h>

#define HID 50
#define FOURH 200
#define TSTEPS 2048
#define NBATCH 1024

typedef _Float16 v2h __attribute__((ext_vector_type(2)));

#define LOG2E 1.44269504f

__device__ __forceinline__ float frcp(float x)  { return __builtin_amdgcn_rcpf(x); }
__device__ __forceinline__ float fexp2(float x) { return __builtin_amdgcn_exp2f(x); }

// Gate pre-activations are pre-scaled by log2(e) (weights/bias scaled at load):
// sigmoid(x) = 1/(1+2^(-x*log2e)) : zp = x*log2e already
__device__ __forceinline__ float sigmoid_p(float zp) {
    return frcp(1.0f + fexp2(-zp));
}
// tanh(x) with zp = x*log2e
__device__ __forceinline__ float tanh_p(float zp) {
    return 1.0f - 2.0f * frcp(fexp2(2.0f * zp) + 1.0f);
}
// plain tanh (for c, which is not pre-scaled)
__device__ __forceinline__ float fast_tanh(float x) {
    return 1.0f - 2.0f * frcp(fexp2((2.0f * LOG2E) * x) + 1.0f);
}

__device__ __forceinline__ v2h bc_v2h(unsigned int u) {
    return __builtin_bit_cast(v2h, u);
}

// One wave per batch (1024 waves = 1/SIMD). Lane l owns hidden unit min(l,49).
// Recurrent broadcast of h is done WITHOUT LDS: each lane converts its h to
// f16 (RTN), fetches its right neighbor's f16 via DPP row_shl:1 (pairs
// (2k,2k+1) never cross a 16-lane row), packs a half2, and 25 v_readlane ops
// lift the even lanes' packed pairs into SGPRs. v_dot2_f32_f16 (VOP3P) reads
// the SGPR directly as its broadcast operand -> no lgkmcnt on the recurrence
// critical path, no uint4 unpack movs. Wx/Wh/bias pre-scaled by log2(e) to
// drop one v_mul from each gate's transcendental chain.
// (Round 1 note: resubmission of Round 0 kernel — previous bench died to an
// MI355X container infra failure with no compile/run diagnostic.)
__global__ __launch_bounds__(64, 1)
void lstm_rlane_kernel(const float* __restrict__ x,
                       const float* __restrict__ Wx,
                       const float* __restrict__ Wh,
                       const float* __restrict__ bias,
                       const float* __restrict__ Wd,
                       const float* __restrict__ bd,
                       float* __restrict__ out) {
    const int b    = blockIdx.x;
    const int lane = threadIdx.x;
    const int lc   = (lane < HID) ? lane : (HID - 1);

    __shared__ __align__(16) float xs[TSTEPS + 4];

    // Stage x (coalesced float4 loads). Read in-loop as uniform ds_read_b32,
    // prefetched one step ahead (off the critical path).
    const float4* xb4 = (const float4*)(x + (size_t)b * TSTEPS);
    float4* xs4 = (float4*)xs;
    #pragma unroll
    for (int i = lane; i < TSTEPS / 4; i += 64) xs4[i] = xb4[i];
    if (lane == 0) xs[TSTEPS] = 0.0f;

    // Per-unit recurrent weights for all 4 gates, packed along k as half2
    // (25 pairs = k 0..49), pre-scaled by log2(e).
    v2h wi[25], wf[25], wg[25], wo[25];
    #pragma unroll
    for (int k2 = 0; k2 < 25; ++k2) {
        const float* r0 = Wh + (2 * k2) * FOURH;
        const float* r1 = Wh + (2 * k2 + 1) * FOURH;
        wi[k2] = v2h{(_Float16)(LOG2E * r0[lc]),           (_Float16)(LOG2E * r1[lc])};
        wf[k2] = v2h{(_Float16)(LOG2E * r0[HID + lc]),     (_Float16)(LOG2E * r1[HID + lc])};
        wg[k2] = v2h{(_Float16)(LOG2E * r0[2 * HID + lc]), (_Float16)(LOG2E * r1[2 * HID + lc])};
        wo[k2] = v2h{(_Float16)(LOG2E * r0[3 * HID + lc]), (_Float16)(LOG2E * r1[3 * HID + lc])};
    }
    const float wx_i = LOG2E * Wx[lc],           b_i = LOG2E * bias[lc];
    const float wx_f = LOG2E * Wx[HID + lc],     b_f = LOG2E * bias[HID + lc];
    const float wx_g = LOG2E * Wx[2 * HID + lc], b_g = LOG2E * bias[2 * HID + lc];
    const float wx_o = LOG2E * Wx[3 * HID + lc], b_o = LOG2E * bias[3 * HID + lc];

    float c = 0.0f;
    float h = 0.0f;
    __syncthreads();   // one-time: x staging visible

    float xt = xs[0];

    for (int t = 0; t < TSTEPS; ++t) {
        const float xt_next = xs[t + 1];

        // Pack (h[2k], h[2k+1]) as half2 on even lanes; broadcast via readlane.
        const unsigned h16  = (unsigned)__builtin_bit_cast(unsigned short, (_Float16)h);
        const unsigned h16n = (unsigned)__builtin_amdgcn_update_dpp(
            0, (int)h16, 0x101 /*row_shl:1 -> lane i gets lane i+1*/, 0xf, 0xf, true);
        const unsigned hp = h16 | (h16n << 16);

        unsigned sh[25];
        #pragma unroll
        for (int k = 0; k < 25; ++k)
            sh[k] = (unsigned)__builtin_amdgcn_readlane((int)hp, 2 * k);

        // 8 independent dot2 chains (2 per gate), SGPR broadcast operand.
        float ai0 = 0.f, ai1 = 0.f, af0 = 0.f, af1 = 0.f;
        float ag0 = 0.f, ag1 = 0.f, ao0 = 0.f, ao1 = 0.f;
        #pragma unroll
        for (int j = 0; j < 12; ++j) {
            const v2h h0 = bc_v2h(sh[2 * j]);
            const v2h h1 = bc_v2h(sh[2 * j + 1]);
            ai0 = __builtin_amdgcn_fdot2(wi[2 * j],     h0, ai0, false);
            af0 = __builtin_amdgcn_fdot2(wf[2 * j],     h0, af0, false);
            ag0 = __builtin_amdgcn_fdot2(wg[2 * j],     h0, ag0, false);
            ao0 = __builtin_amdgcn_fdot2(wo[2 * j],     h0, ao0, false);
            ai1 = __builtin_amdgcn_fdot2(wi[2 * j + 1], h1, ai1, false);
            af1 = __builtin_amdgcn_fdot2(wf[2 * j + 1], h1, af1, false);
            ag1 = __builtin_amdgcn_fdot2(wg[2 * j + 1], h1, ag1, false);
            ao1 = __builtin_amdgcn_fdot2(wo[2 * j + 1], h1, ao1, false);
        }
        {   // pair 24 (h48,h49)
            const v2h hp24 = bc_v2h(sh[24]);
            ai0 = __builtin_amdgcn_fdot2(wi[24], hp24, ai0, false);
            af0 = __builtin_amdgcn_fdot2(wf[24], hp24, af0, false);
            ag0 = __builtin_amdgcn_fdot2(wg[24], hp24, ag0, false);
            ao0 = __builtin_amdgcn_fdot2(wo[24], hp24, ao0, false);
        }

        const float zi = fmaf(xt, wx_i, b_i) + (ai0 + ai1);
        const float zf = fmaf(xt, wx_f, b_f) + (af0 + af1);
        const float zg = fmaf(xt, wx_g, b_g) + (ag0 + ag1);
        const float zo = fmaf(xt, wx_o, b_o) + (ao0 + ao1);

        const float ig = sigmoid_p(zi);
        const float fg = sigmoid_p(zf);
        const float gg = tanh_p(zg);
        const float og = sigmoid_p(zo);
        c = fmaf(fg, c, ig * gg);
        h = og * fast_tanh(c);

        xt = xt_next;
    }

    // out[b] = h_T . Wd + bd  (fp32 h from registers)
    float v = (lane < HID) ? h * Wd[lane] : 0.0f;
    #pragma unroll
    for (int off = 32; off > 0; off >>= 1) v += __shfl_down(v, off);
    if (lane == 0) out[b] = v + bd[0];
}

extern "C" void kernel_launch(void* const* d_in, const int* in_sizes, int n_in,
                              void* d_out, int out_size, void* d_ws, size_t ws_size,
                              hipStream_t stream) {
    const float* x    = (const float*)d_in[0];  // [1024, 2048, 1]
    const float* Wx   = (const float*)d_in[1];  // [1, 200]
    const float* Wh   = (const float*)d_in[2];  // [50, 200]
    const float* bias = (const float*)d_in[3];  // [200]
    const float* Wd   = (const float*)d_in[4];  // [50, 1]
    const float* bd   = (const float*)d_in[5];  // [1]
    float* out = (float*)d_out;                 // [1024, 1]

    lstm_rlane_kernel<<<dim3(NBATCH), dim3(64), 0, stream>>>(
        x, Wx, Wh, bias, Wd, bd, out);
}